// Round 7
// baseline (232.043 us; speedup 1.0000x reference)
//
#include <hip/hip_runtime.h>

#define LOG2E 1.4426950408889634f

typedef __attribute__((ext_vector_type(8))) short short8;
typedef __attribute__((ext_vector_type(4))) float f32x4;
using u32 = unsigned int;
using u16 = unsigned short;
using u64 = unsigned long long;

// ---------------------------------------------------------------------------
// Kernel P: pack adj (4096x4096 int32 0/1) into transposed bitmask.
// ---------------------------------------------------------------------------
__global__ __launch_bounds__(256) void pack_mask_kernel(const int* __restrict__ adj,
                                                        u32* __restrict__ mask_t) {
    const int wid = (blockIdx.x * 256 + threadIdx.x) >> 6;
    const int lane = threadIdx.x & 63;
    for (int t = wid; t < 65536; t += 8192) {          // task = (row, 4-chunk group)
        const int r = t >> 4, c4 = t & 15;
        const int* base = adj + (size_t)r * 4096 + c4 * 256 + lane;
        int v0 = __builtin_nontemporal_load(base);
        int v1 = __builtin_nontemporal_load(base + 64);
        int v2 = __builtin_nontemporal_load(base + 128);
        int v3 = __builtin_nontemporal_load(base + 192);
        u64 b0 = __ballot(v0 > 0);
        u64 b1 = __ballot(v1 > 0);
        u64 b2 = __ballot(v2 > 0);
        u64 b3 = __ballot(v3 > 0);
        if (lane < 8) {                                 // lane k stores word-col c4*8+k
            u64 bv = (lane & 4) ? ((lane & 2) ? b3 : b2) : ((lane & 2) ? b1 : b0);
            u32 w = (u32)(bv >> ((lane & 1) << 5));
            mask_t[(size_t)(c4 * 8 + lane) * 4096 + r] = w;
        }
    }
}

// ---------------------------------------------------------------------------
// Kernel 1: h-partial = x @ W over one K-segment (K-split KS=4).
// ---------------------------------------------------------------------------
__global__ __launch_bounds__(256) void k1_xw(const float* __restrict__ x,
                                             const float* __restrict__ W,
                                             float* __restrict__ ph,
                                             int TILES) {
    __shared__ float xs[64][36];
    __shared__ float ws[32][64];
    const int b = blockIdx.y, rt = blockIdx.x, ks = blockIdx.z;
    const int tid = threadIdx.x;
    const int rg = tid >> 4, cg = tid & 15;
    const int r0 = rg * 4, c0 = cg * 4;
    const int kt0 = ks * TILES;
    const float* xb = x + ((size_t)b * 4096 + (size_t)rt * 64) * 512;

    float acc[4][4];
#pragma unroll
    for (int i = 0; i < 4; i++)
#pragma unroll
        for (int j = 0; j < 4; j++) acc[i][j] = 0.f;

    float4 px[2], pw[2];
#pragma unroll
    for (int it = 0; it < 2; it++) {
        int c = tid + it * 256;
        px[it] = *(const float4*)(xb + (size_t)(c >> 3) * 512 + kt0 * 32 + ((c & 7) << 2));
        pw[it] = *(const float4*)(W + (size_t)(kt0 * 32 + (c >> 4)) * 64 + ((c & 15) << 2));
    }
    for (int kt = kt0; kt < kt0 + TILES; kt++) {
        __syncthreads();
#pragma unroll
        for (int it = 0; it < 2; it++) {
            int c = tid + it * 256;
            *(float4*)&xs[c >> 3][(c & 7) << 2] = px[it];
            *(float4*)&ws[c >> 4][(c & 15) << 2] = pw[it];
        }
        __syncthreads();
        if (kt < kt0 + TILES - 1) {
            int k0 = (kt + 1) * 32;
#pragma unroll
            for (int it = 0; it < 2; it++) {
                int c = tid + it * 256;
                px[it] = *(const float4*)(xb + (size_t)(c >> 3) * 512 + k0 + ((c & 7) << 2));
                pw[it] = *(const float4*)(W + (size_t)(k0 + (c >> 4)) * 64 + ((c & 15) << 2));
            }
        }
#pragma unroll
        for (int k4 = 0; k4 < 32; k4 += 4) {
            float4 xv[4], wv[4];
#pragma unroll
            for (int rr = 0; rr < 4; rr++) xv[rr] = *(const float4*)&xs[r0 + rr][k4];
#pragma unroll
            for (int kk = 0; kk < 4; kk++) wv[kk] = *(const float4*)&ws[k4 + kk][c0];
#pragma unroll
            for (int rr = 0; rr < 4; rr++)
#pragma unroll
                for (int kk = 0; kk < 4; kk++) {
                    const float xvv = ((const float*)&xv[rr])[kk];
#pragma unroll
                    for (int cc = 0; cc < 4; cc++)
                        acc[rr][cc] = fmaf(xvv, ((const float*)&wv[kk])[cc], acc[rr][cc]);
                }
        }
    }
    float* pb = ph + (((size_t)(ks * 4 + b) * 4096) + rt * 64) * 64;
#pragma unroll
    for (int rr = 0; rr < 4; rr++)
        *(float4*)&pb[(size_t)(r0 + rr) * 64 + c0] = *(float4*)&acc[rr][0];
}

// ---------------------------------------------------------------------------
// Kernel 1c: sum K-split partials; epilogue: s1/s2 (pre-scaled), h^T bf16.
// ---------------------------------------------------------------------------
template <int KS>
__global__ __launch_bounds__(256) void k1c_fin(const float* __restrict__ ph,
                                               const float* __restrict__ a,
                                               u16* __restrict__ h_t,
                                               float* __restrict__ s1p,
                                               float* __restrict__ s2p) {
    const int b = blockIdx.y, rt = blockIdx.x;
    const int tid = threadIdx.x;
    const int rg = tid >> 4, cg = tid & 15;
    const int r0 = rg * 4, c0 = cg * 4;

    float4 v[KS][4];
#pragma unroll
    for (int s = 0; s < KS; s++) {
        const float* pb = ph + (((size_t)(s * 4 + b) * 4096) + rt * 64) * 64;
#pragma unroll
        for (int rr = 0; rr < 4; rr++)
            v[s][rr] = *(const float4*)&pb[(size_t)(r0 + rr) * 64 + c0];
    }
    float acc[4][4];
#pragma unroll
    for (int rr = 0; rr < 4; rr++) {
        acc[rr][0] = acc[rr][1] = acc[rr][2] = acc[rr][3] = 0.f;
#pragma unroll
        for (int s = 0; s < KS; s++) {
            acc[rr][0] += v[s][rr].x; acc[rr][1] += v[s][rr].y;
            acc[rr][2] += v[s][rr].z; acc[rr][3] += v[s][rr].w;
        }
    }
    float s1v[4], s2v[4];
#pragma unroll
    for (int rr = 0; rr < 4; rr++) { s1v[rr] = 0.f; s2v[rr] = 0.f; }
#pragma unroll
    for (int cc = 0; cc < 4; cc++) {
        float a1 = a[c0 + cc], a2 = a[64 + c0 + cc];
#pragma unroll
        for (int rr = 0; rr < 4; rr++) {
            s1v[rr] = fmaf(acc[rr][cc], a1, s1v[rr]);
            s2v[rr] = fmaf(acc[rr][cc], a2, s2v[rr]);
        }
    }
#pragma unroll
    for (int d = 1; d < 16; d <<= 1) {
#pragma unroll
        for (int rr = 0; rr < 4; rr++) {
            s1v[rr] += __shfl_xor(s1v[rr], d);
            s2v[rr] += __shfl_xor(s2v[rr], d);
        }
    }
    if (cg == 0) {
#pragma unroll
        for (int rr = 0; rr < 4; rr++) {
            int row = rt * 64 + r0 + rr;
            s1p[b * 4096 + row] = s1v[rr] * LOG2E;
            s2p[b * 4096 + row] = s2v[rr] * LOG2E;
        }
    }
#pragma unroll
    for (int cc = 0; cc < 4; cc++) {
        u32 b0 = __float_as_uint(acc[0][cc]) + 0x8000u;
        u32 b1 = __float_as_uint(acc[1][cc]) + 0x8000u;
        u32 b2 = __float_as_uint(acc[2][cc]) + 0x8000u;
        u32 b3 = __float_as_uint(acc[3][cc]) + 0x8000u;
        uint2 u;
        u.x = (b0 >> 16) | (b1 & 0xffff0000u);
        u.y = (b2 >> 16) | (b3 & 0xffff0000u);
        *(uint2*)(h_t + ((size_t)(b * 64 + c0 + cc)) * 4096 + rt * 64 + r0) = u;
    }
}

// ---------------------------------------------------------------------------
// Kernel 2: fused masked-softmax-numerator GEMM.
// Locality remap (r6 finding: co-resident WGs shared NOTHING; B-stream is
// rb-independent): blockIdx = (bseg, rb); co-resident WG ids differ by 256
// and 256 % 16 == 0, so all 4 WGs/CU share (b,seg) -> identical B-stream
// (L1 reuse); per-XCD set = 2 bsegs (~256 KB B + 1 MB mask) -> L2-resident
// despite the part-write stream.
// Pipeline: B-frags 4-slot (&3) window at prefetch distance 2 (~2 bodies
// > L2 latency); mask rolling 4-deep window at distance 4 (consume before
// overwrite: (s+4)&3 == s&3); s2 via LDS (lgkm counter). ~108 VGPR, no spill.
// ---------------------------------------------------------------------------
template <int NSTEP>
__global__ __launch_bounds__(256, 4) void k2_attn(const u16* __restrict__ h_t,
                                                  const u32* __restrict__ mask_t,
                                                  const float* __restrict__ s1p,
                                                  const float* __restrict__ s2p,
                                                  float* __restrict__ part,
                                                  float* __restrict__ lp) {
    constexpr int JSEG = NSTEP * 32;
    __shared__ float s2l[JSEG];
    const int bseg = blockIdx.x, rb = blockIdx.y;
    const int b = bseg >> 2, seg = bseg & 3;
    const int tid = threadIdx.x, wave = tid >> 6, lane = tid & 63;
    const int m = lane & 15, quad = lane >> 4;
    const int row = rb * 64 + wave * 16 + m;
    const int jstart = seg * JSEG;
    const float t1 = s1p[b * 4096 + row];
    const u16* hb0 = h_t + ((size_t)b * 64 + m) * 4096 + jstart + quad * 8;
    const u32* mrow = mask_t + (size_t)(jstart >> 5) * 4096 + row;

    for (int t = tid; t < (JSEG >> 2); t += 256)
        ((float4*)s2l)[t] = ((const float4*)(s2p + b * 4096 + jstart))[t];

    f32x4 acc[4];
#pragma unroll
    for (int ot = 0; ot < 4; ot++) acc[ot] = (f32x4){0.f, 0.f, 0.f, 0.f};
    float lsA = 0.f, lsB = 0.f;

    union BU { uint4 q; short8 v; };
    BU bf[4][4];               // 4-slot B window, distance-2 prefetch
    u32 mw[4];
#pragma unroll
    for (int s = 0; s < 4; s++) mw[s] = mrow[(size_t)s * 4096];   // mask window 0..3
#pragma unroll
    for (int s = 0; s < 2; s++)                                    // B steps 0,1
#pragma unroll
        for (int ot = 0; ot < 4; ot++)
            bf[s][ot].q = *(const uint4*)(hb0 + s * 32 + (size_t)ot * 16 * 4096);
    __syncthreads();   // s2l ready (only barrier in the kernel)

#pragma unroll 4
    for (int s = 0; s < NSTEP; s++) {
        // READ the current mask word FIRST (slot (s+4)&3 aliases s&3)
        const u32 mws = mw[s & 3] >> (quad * 8);
        if (s + 2 < NSTEP) {       // B prefetch, 2 iters ahead (slot (s+2)&3 is free)
#pragma unroll
            for (int ot = 0; ot < 4; ot++)
                bf[(s + 2) & 3][ot].q =
                    *(const uint4*)(hb0 + (s + 2) * 32 + (size_t)ot * 16 * 4096);
        }
        if (s + 4 < NSTEP)         // mask prefetch, 4 iters ahead (stays oldest)
            mw[(s + 4) & 3] = mrow[(size_t)(s + 4) * 4096];

        const float4 sa = *(const float4*)&s2l[s * 32 + quad * 8];
        const float4 sb = *(const float4*)&s2l[s * 32 + quad * 8 + 4];
        const float sv[8] = {sa.x, sa.y, sa.z, sa.w, sb.x, sb.y, sb.z, sb.w};
        union { u32 u[4]; short8 v; } af;
#pragma unroll
        for (int p = 0; p < 4; p++) {
            float t0 = t1 + sv[2 * p];
            float u0 = fmaxf(t0, 0.2f * t0);                     // leaky-relu (log2 domain)
            float w0 = __builtin_amdgcn_exp2f(u0);
            u32 m0 = (u32)(((int)(mws << (31 - 2 * p))) >> 31);  // bit -> all-ones/0
            u32 w0u = __float_as_uint(w0) & m0;                  // masked -> +0.0
            float t2 = t1 + sv[2 * p + 1];
            float u2 = fmaxf(t2, 0.2f * t2);
            float w1 = __builtin_amdgcn_exp2f(u2);
            u32 m1 = (u32)(((int)(mws << (30 - 2 * p))) >> 31);
            u32 w1u = __float_as_uint(w1) & m1;
            lsA += __uint_as_float(w0u);                         // denom (pre-round)
            lsB += __uint_as_float(w1u);
            // round-half-up bf16 pack: hi16 of (w+0x8000)
            af.u[p] = __builtin_amdgcn_perm(w1u + 0x8000u, w0u + 0x8000u, 0x07060302u);
        }
#pragma unroll
        for (int ot = 0; ot < 4; ot++)
            acc[ot] = __builtin_amdgcn_mfma_f32_16x16x32_bf16(af.v, bf[s & 3][ot].v,
                                                              acc[ot], 0, 0, 0);
    }
    // C/D layout: col=lane&15 (=o sub-index), row=quad*4+reg (=attention row)
    float* pb = part + (((size_t)(seg * 4 + b) * 4096) + rb * 64 + wave * 16) * 64;
#pragma unroll
    for (int ot = 0; ot < 4; ot++)
#pragma unroll
        for (int r = 0; r < 4; r++)
            pb[(quad * 4 + r) * 64 + ot * 16 + m] = acc[ot][r];
    lp[((size_t)(seg * 4 + b) * 4096 + row) * 4 + quad] = lsA + lsB;
}

// ---------------------------------------------------------------------------
// Kernel 3: combine j-split partials, normalize, elu.
// ---------------------------------------------------------------------------
template <int S>
__global__ __launch_bounds__(256) void k3_fin(const float* __restrict__ part,
                                              const float* __restrict__ lp,
                                              float* __restrict__ out) {
    int idx = blockIdx.x * 256 + threadIdx.x;    // 262144 = 4*4096*16
    int o4 = (idx & 15) << 2;
    int bi = idx >> 4;
    float4 pv[S], lv[S];
#pragma unroll
    for (int s = 0; s < S; s++) {
        pv[s] = *(const float4*)&part[((size_t)s * 16384 + bi) * 64 + o4];
        lv[s] = *(const float4*)&lp[((size_t)s * 16384 + bi) * 4];
    }
    float p0 = 0.f, p1 = 0.f, p2 = 0.f, p3 = 0.f, l = 0.f;
#pragma unroll
    for (int s = 0; s < S; s++) {
        p0 += pv[s].x; p1 += pv[s].y; p2 += pv[s].z; p3 += pv[s].w;
        l += (lv[s].x + lv[s].y) + (lv[s].z + lv[s].w);
    }
    float rl = 1.f / l;
    p0 *= rl; p1 *= rl; p2 *= rl; p3 *= rl;
    float4 o;
    o.x = p0 > 0.f ? p0 : __builtin_amdgcn_exp2f(p0 * LOG2E) - 1.f;
    o.y = p1 > 0.f ? p1 : __builtin_amdgcn_exp2f(p1 * LOG2E) - 1.f;
    o.z = p2 > 0.f ? p2 : __builtin_amdgcn_exp2f(p2 * LOG2E) - 1.f;
    o.w = p3 > 0.f ? p3 : __builtin_amdgcn_exp2f(p3 * LOG2E) - 1.f;
    *(float4*)&out[(size_t)bi * 64 + o4] = o;
}

// ---------------------------------------------------------------------------
extern "C" void kernel_launch(void* const* d_in, const int* in_sizes, int n_in,
                              void* d_out, int out_size, void* d_ws, size_t ws_size,
                              hipStream_t stream) {
    const float* x  = (const float*)d_in[0];
    const int* adj  = (const int*)d_in[1];
    const float* W  = (const float*)d_in[2];
    const float* a  = (const float*)d_in[3];
    float* out = (float*)d_out;
    char* ws = (char*)d_ws;

    // workspace layout
    u16* h_t   = (u16*)ws;                         // 2 MB
    u32* maskt = (u32*)(ws + (2 << 20));           // 2 MB
    float* s1p = (float*)(ws + (4 << 20));         // 64 KB
    float* s2p = s1p + 16384;                      // 64 KB
    float* lp  = s2p + 16384;                      // S*256 KB
    size_t base = (4u << 20) + 2 * 65536;
    int S = 4;                                     // k2 j-split: 1024 WGs = 4 WGs/CU
    while (S > 1 && base + (size_t)S * (262144 + 4194304) > ws_size) S >>= 1;
    float* part = (float*)(ws + base + (size_t)S * 262144);   // S*4 MB
    // k1 K-split partials alias the part buffer (free until k2 writes it)
    int KS = 4;
    while (KS > 1 && base + (size_t)S * 262144 + (size_t)KS * 4194304 > ws_size) KS >>= 1;

    pack_mask_kernel<<<2048, 256, 0, stream>>>(adj, maskt);
    k1_xw<<<dim3(64, 4, KS), 256, 0, stream>>>(x, W, part, 16 / KS);
    if (KS == 4)      k1c_fin<4><<<dim3(64, 4), 256, 0, stream>>>(part, a, h_t, s1p, s2p);
    else if (KS == 2) k1c_fin<2><<<dim3(64, 4), 256, 0, stream>>>(part, a, h_t, s1p, s2p);
    else              k1c_fin<1><<<dim3(64, 4), 256, 0, stream>>>(part, a, h_t, s1p, s2p);
    // blockIdx.x = bseg = b*4+seg (16), blockIdx.y = rb (64)
    if (S == 4)      k2_attn<32><<<dim3(16, 64), 256, 0, stream>>>(h_t, maskt, s1p, s2p, part, lp);
    else if (S == 2) k2_attn<64><<<dim3(8, 64), 256, 0, stream>>>(h_t, maskt, s1p, s2p, part, lp);
    else             k2_attn<128><<<dim3(4, 64), 256, 0, stream>>>(h_t, maskt, s1p, s2p, part, lp);
    if (S == 4)      k3_fin<4><<<1024, 256, 0, stream>>>(part, lp, out);
    else if (S == 2) k3_fin<2><<<1024, 256, 0, stream>>>(part, lp, out);
    else             k3_fin<1><<<1024, 256, 0, stream>>>(part, lp, out);
}

// Round 8
// 202.699 us; speedup vs baseline: 1.1448x; 1.1448x over previous
//
#include <hip/hip_runtime.h>

#define LOG2E 1.4426950408889634f

typedef __attribute__((ext_vector_type(8))) short short8;
typedef __attribute__((ext_vector_type(4))) float f32x4;
using u32 = unsigned int;
using u16 = unsigned short;
using u64 = unsigned long long;

// ---------------------------------------------------------------------------
// Kernel P: pack adj (4096x4096 int32 0/1) into transposed bitmask.
// ---------------------------------------------------------------------------
__global__ __launch_bounds__(256) void pack_mask_kernel(const int* __restrict__ adj,
                                                        u32* __restrict__ mask_t) {
    const int wid = (blockIdx.x * 256 + threadIdx.x) >> 6;
    const int lane = threadIdx.x & 63;
    for (int t = wid; t < 65536; t += 8192) {          // task = (row, 4-chunk group)
        const int r = t >> 4, c4 = t & 15;
        const int* base = adj + (size_t)r * 4096 + c4 * 256 + lane;
        int v0 = __builtin_nontemporal_load(base);
        int v1 = __builtin_nontemporal_load(base + 64);
        int v2 = __builtin_nontemporal_load(base + 128);
        int v3 = __builtin_nontemporal_load(base + 192);
        u64 b0 = __ballot(v0 > 0);
        u64 b1 = __ballot(v1 > 0);
        u64 b2 = __ballot(v2 > 0);
        u64 b3 = __ballot(v3 > 0);
        if (lane < 8) {                                 // lane k stores word-col c4*8+k
            u64 bv = (lane & 4) ? ((lane & 2) ? b3 : b2) : ((lane & 2) ? b1 : b0);
            u32 w = (u32)(bv >> ((lane & 1) << 5));
            mask_t[(size_t)(c4 * 8 + lane) * 4096 + r] = w;
        }
    }
}

// ---------------------------------------------------------------------------
// Kernel W: transpose W (512x64 fp32) -> Wt[64][512] bf16 (round-half-up).
// 64 KB result is L2/L1-hot for k1_mfma's B-frag loads.
// ---------------------------------------------------------------------------
__global__ __launch_bounds__(256) void wt_prep(const float* __restrict__ W,
                                               u16* __restrict__ wt) {
    int t = blockIdx.x * 256 + threadIdx.x;            // 8192 threads
    int n = t >> 7, k4 = (t & 127) << 2;
    u32 c0 = __float_as_uint(W[(size_t)(k4 + 0) * 64 + n]) + 0x8000u;
    u32 c1 = __float_as_uint(W[(size_t)(k4 + 1) * 64 + n]) + 0x8000u;
    u32 c2 = __float_as_uint(W[(size_t)(k4 + 2) * 64 + n]) + 0x8000u;
    u32 c3 = __float_as_uint(W[(size_t)(k4 + 3) * 64 + n]) + 0x8000u;
    uint2 o;
    o.x = (c0 >> 16) | (c1 & 0xffff0000u);
    o.y = (c2 >> 16) | (c3 & 0xffff0000u);
    *(uint2*)(wt + (size_t)n * 512 + k4) = o;
}

// ---------------------------------------------------------------------------
// Kernel 1: h-partial = x @ W via bf16 MFMA, barrier-free, no LDS.
// Replaces the fp32-VALU k1_xw (~50 us, LDS-latency-stalled at 4 waves/SIMD).
// Per wave: 16 rows x 64 cols, K=256 (KS=2 split -> 2048 waves = 2/SIMD).
// A-frag: two float4 direct loads of x + round-half-up bf16 pack in-reg.
// B-frag: 16 B direct loads from Wt (64 KB, L1-hot, shared by all waves).
// Depth-2 windows; consume-before-prefetch (r5 lesson). fp32 partials -> k1c.
// ---------------------------------------------------------------------------
__global__ __launch_bounds__(256) void k1_mfma(const float* __restrict__ x,
                                               const u16* __restrict__ wt,
                                               float* __restrict__ ph) {
    const int rt = blockIdx.x, b = blockIdx.y, kz = blockIdx.z;
    const int tid = threadIdx.x, wave = tid >> 6, lane = tid & 63;
    const int m = lane & 15, quad = lane >> 4;
    const int row = rt * 64 + wave * 16 + m;
    const float* xb = x + ((size_t)b * 4096 + row) * 512 + kz * 256 + quad * 8;
    const u16* wb = wt + (size_t)m * 512 + kz * 256 + quad * 8;

    f32x4 acc[4];
#pragma unroll
    for (int ot = 0; ot < 4; ot++) acc[ot] = (f32x4){0.f, 0.f, 0.f, 0.f};

    union BU { uint4 q; short8 v; };
    float4 ax[2][2];
    BU bw[2][4];
#pragma unroll
    for (int s = 0; s < 2; s++) {          // preload k-steps 0,1
        ax[s][0] = *(const float4*)(xb + s * 32);
        ax[s][1] = *(const float4*)(xb + s * 32 + 4);
#pragma unroll
        for (int ot = 0; ot < 4; ot++)
            bw[s][ot].q = *(const uint4*)(wb + (size_t)ot * 16 * 512 + s * 32);
    }
#pragma unroll
    for (int s = 0; s < 8; s++) {          // K=256 in 8 steps of 32
        const int cur = s & 1;
        union { u32 u[4]; short8 v; } af;
        const float* a0 = (const float*)&ax[cur][0];
#pragma unroll
        for (int p = 0; p < 4; p++) {      // round-half-up bf16 pack (lo=k even)
            u32 lo = __float_as_uint(a0[2 * p]) + 0x8000u;
            u32 hi = __float_as_uint(a0[2 * p + 1]) + 0x8000u;
            af.u[p] = __builtin_amdgcn_perm(hi, lo, 0x07060302u);
        }
#pragma unroll
        for (int ot = 0; ot < 4; ot++)
            acc[ot] = __builtin_amdgcn_mfma_f32_16x16x32_bf16(af.v, bw[cur][ot].v,
                                                              acc[ot], 0, 0, 0);
        if (s + 2 < 8) {                   // prefetch after consumption
            ax[cur][0] = *(const float4*)(xb + (s + 2) * 32);
            ax[cur][1] = *(const float4*)(xb + (s + 2) * 32 + 4);
#pragma unroll
            for (int ot = 0; ot < 4; ot++)
                bw[cur][ot].q =
                    *(const uint4*)(wb + (size_t)ot * 16 * 512 + (s + 2) * 32);
        }
    }
    // C/D layout: col=lane&15 (n sub-index), row=quad*4+reg
    float* pb = ph + (((size_t)(kz * 4 + b) * 4096) + rt * 64 + wave * 16) * 64;
#pragma unroll
    for (int ot = 0; ot < 4; ot++)
#pragma unroll
        for (int r = 0; r < 4; r++)
            pb[(quad * 4 + r) * 64 + ot * 16 + m] = acc[ot][r];
}

// ---------------------------------------------------------------------------
// Kernel 1c: sum K-split partials; epilogue: s1/s2 (pre-scaled), h^T bf16.
// ---------------------------------------------------------------------------
template <int KS>
__global__ __launch_bounds__(256) void k1c_fin(const float* __restrict__ ph,
                                               const float* __restrict__ a,
                                               u16* __restrict__ h_t,
                                               float* __restrict__ s1p,
                                               float* __restrict__ s2p) {
    const int b = blockIdx.y, rt = blockIdx.x;
    const int tid = threadIdx.x;
    const int rg = tid >> 4, cg = tid & 15;
    const int r0 = rg * 4, c0 = cg * 4;

    float4 v[KS][4];
#pragma unroll
    for (int s = 0; s < KS; s++) {
        const float* pb = ph + (((size_t)(s * 4 + b) * 4096) + rt * 64) * 64;
#pragma unroll
        for (int rr = 0; rr < 4; rr++)
            v[s][rr] = *(const float4*)&pb[(size_t)(r0 + rr) * 64 + c0];
    }
    float acc[4][4];
#pragma unroll
    for (int rr = 0; rr < 4; rr++) {
        acc[rr][0] = acc[rr][1] = acc[rr][2] = acc[rr][3] = 0.f;
#pragma unroll
        for (int s = 0; s < KS; s++) {
            acc[rr][0] += v[s][rr].x; acc[rr][1] += v[s][rr].y;
            acc[rr][2] += v[s][rr].z; acc[rr][3] += v[s][rr].w;
        }
    }
    float s1v[4], s2v[4];
#pragma unroll
    for (int rr = 0; rr < 4; rr++) { s1v[rr] = 0.f; s2v[rr] = 0.f; }
#pragma unroll
    for (int cc = 0; cc < 4; cc++) {
        float a1 = a[c0 + cc], a2 = a[64 + c0 + cc];
#pragma unroll
        for (int rr = 0; rr < 4; rr++) {
            s1v[rr] = fmaf(acc[rr][cc], a1, s1v[rr]);
            s2v[rr] = fmaf(acc[rr][cc], a2, s2v[rr]);
        }
    }
#pragma unroll
    for (int d = 1; d < 16; d <<= 1) {
#pragma unroll
        for (int rr = 0; rr < 4; rr++) {
            s1v[rr] += __shfl_xor(s1v[rr], d);
            s2v[rr] += __shfl_xor(s2v[rr], d);
        }
    }
    if (cg == 0) {
#pragma unroll
        for (int rr = 0; rr < 4; rr++) {
            int row = rt * 64 + r0 + rr;
            s1p[b * 4096 + row] = s1v[rr] * LOG2E;
            s2p[b * 4096 + row] = s2v[rr] * LOG2E;
        }
    }
#pragma unroll
    for (int cc = 0; cc < 4; cc++) {
        u32 b0 = __float_as_uint(acc[0][cc]) + 0x8000u;
        u32 b1 = __float_as_uint(acc[1][cc]) + 0x8000u;
        u32 b2 = __float_as_uint(acc[2][cc]) + 0x8000u;
        u32 b3 = __float_as_uint(acc[3][cc]) + 0x8000u;
        uint2 u;
        u.x = (b0 >> 16) | (b1 & 0xffff0000u);
        u.y = (b2 >> 16) | (b3 & 0xffff0000u);
        *(uint2*)(h_t + ((size_t)(b * 64 + c0 + cc)) * 4096 + rt * 64 + r0) = u;
    }
}

// ---------------------------------------------------------------------------
// Kernel 2: fused masked-softmax-numerator GEMM — r6-exact (66 us verified;
// r7's bseg remap + 4-slot window regressed to 73 and is reverted).
// ---------------------------------------------------------------------------
template <int NSTEP>
__global__ __launch_bounds__(256, 4) void k2_attn(const u16* __restrict__ h_t,
                                                  const u32* __restrict__ mask_t,
                                                  const float* __restrict__ s1p,
                                                  const float* __restrict__ s2p,
                                                  float* __restrict__ part,
                                                  float* __restrict__ lp) {
    constexpr int JSEG = NSTEP * 32;
    __shared__ float s2l[JSEG];
    const int b = blockIdx.y, seg = blockIdx.z, rb = blockIdx.x;
    const int tid = threadIdx.x, wave = tid >> 6, lane = tid & 63;
    const int m = lane & 15, quad = lane >> 4;
    const int row = rb * 64 + wave * 16 + m;
    const int jstart = seg * JSEG;
    const float t1 = s1p[b * 4096 + row];
    const u16* hb0 = h_t + ((size_t)b * 64 + m) * 4096 + jstart + quad * 8;
    const u32* mrow = mask_t + (size_t)(jstart >> 5) * 4096 + row;

    for (int t = tid; t < (JSEG >> 2); t += 256)
        ((float4*)s2l)[t] = ((const float4*)(s2p + b * 4096 + jstart))[t];

    f32x4 acc[4];
#pragma unroll
    for (int ot = 0; ot < 4; ot++) acc[ot] = (f32x4){0.f, 0.f, 0.f, 0.f};
    float lsA = 0.f, lsB = 0.f;

    union BU { uint4 q; short8 v; };
    BU bf[2][4];
    u32 mw[4];
#pragma unroll
    for (int s = 0; s < 4; s++) mw[s] = mrow[(size_t)s * 4096];   // mask window 0..3
#pragma unroll
    for (int ot = 0; ot < 4; ot++)                                 // B step 0
        bf[0][ot].q = *(const uint4*)(hb0 + (size_t)ot * 16 * 4096);
    __syncthreads();   // s2l ready (only barrier in the kernel)

#pragma unroll 4
    for (int s = 0; s < NSTEP; s++) {
        const int cur = s & 1, nxt = cur ^ 1;
        // READ the current mask word FIRST (slot (s+4)&3 aliases s&3)
        const u32 mws = mw[s & 3] >> (quad * 8);
        if (s + 1 < NSTEP) {       // B prefetch, 1 iter ahead
#pragma unroll
            for (int ot = 0; ot < 4; ot++)
                bf[nxt][ot].q = *(const uint4*)(hb0 + (s + 1) * 32 + (size_t)ot * 16 * 4096);
        }
        if (s + 4 < NSTEP)         // mask prefetch, 4 iters ahead (stays oldest)
            mw[(s + 4) & 3] = mrow[(size_t)(s + 4) * 4096];

        const float4 sa = *(const float4*)&s2l[s * 32 + quad * 8];
        const float4 sb = *(const float4*)&s2l[s * 32 + quad * 8 + 4];
        const float sv[8] = {sa.x, sa.y, sa.z, sa.w, sb.x, sb.y, sb.z, sb.w};
        union { u32 u[4]; short8 v; } af;
#pragma unroll
        for (int p = 0; p < 4; p++) {
            float t0 = t1 + sv[2 * p];
            float u0 = fmaxf(t0, 0.2f * t0);                     // leaky-relu (log2 domain)
            float w0 = __builtin_amdgcn_exp2f(u0);
            u32 m0 = (u32)(((int)(mws << (31 - 2 * p))) >> 31);  // bit -> all-ones/0
            u32 w0u = __float_as_uint(w0) & m0;                  // masked -> +0.0
            float t2 = t1 + sv[2 * p + 1];
            float u2 = fmaxf(t2, 0.2f * t2);
            float w1 = __builtin_amdgcn_exp2f(u2);
            u32 m1 = (u32)(((int)(mws << (30 - 2 * p))) >> 31);
            u32 w1u = __float_as_uint(w1) & m1;
            lsA += __uint_as_float(w0u);                         // denom (pre-round)
            lsB += __uint_as_float(w1u);
            // round-half-up bf16 pack: hi16 of (w+0x8000)
            af.u[p] = __builtin_amdgcn_perm(w1u + 0x8000u, w0u + 0x8000u, 0x07060302u);
        }
#pragma unroll
        for (int ot = 0; ot < 4; ot++)
            acc[ot] = __builtin_amdgcn_mfma_f32_16x16x32_bf16(af.v, bf[cur][ot].v,
                                                              acc[ot], 0, 0, 0);
    }
    // C/D layout: col=lane&15 (=o sub-index), row=quad*4+reg (=attention row)
    float* pb = part + (((size_t)(seg * 4 + b) * 4096) + rb * 64 + wave * 16) * 64;
#pragma unroll
    for (int ot = 0; ot < 4; ot++)
#pragma unroll
        for (int r = 0; r < 4; r++)
            pb[(quad * 4 + r) * 64 + ot * 16 + m] = acc[ot][r];
    lp[((size_t)(seg * 4 + b) * 4096 + row) * 4 + quad] = lsA + lsB;
}

// ---------------------------------------------------------------------------
// Kernel 3: combine j-split partials, normalize, elu.
// ---------------------------------------------------------------------------
template <int S>
__global__ __launch_bounds__(256) void k3_fin(const float* __restrict__ part,
                                              const float* __restrict__ lp,
                                              float* __restrict__ out) {
    int idx = blockIdx.x * 256 + threadIdx.x;    // 262144 = 4*4096*16
    int o4 = (idx & 15) << 2;
    int bi = idx >> 4;
    float4 pv[S], lv[S];
#pragma unroll
    for (int s = 0; s < S; s++) {
        pv[s] = *(const float4*)&part[((size_t)s * 16384 + bi) * 64 + o4];
        lv[s] = *(const float4*)&lp[((size_t)s * 16384 + bi) * 4];
    }
    float p0 = 0.f, p1 = 0.f, p2 = 0.f, p3 = 0.f, l = 0.f;
#pragma unroll
    for (int s = 0; s < S; s++) {
        p0 += pv[s].x; p1 += pv[s].y; p2 += pv[s].z; p3 += pv[s].w;
        l += (lv[s].x + lv[s].y) + (lv[s].z + lv[s].w);
    }
    float rl = 1.f / l;
    p0 *= rl; p1 *= rl; p2 *= rl; p3 *= rl;
    float4 o;
    o.x = p0 > 0.f ? p0 : __builtin_amdgcn_exp2f(p0 * LOG2E) - 1.f;
    o.y = p1 > 0.f ? p1 : __builtin_amdgcn_exp2f(p1 * LOG2E) - 1.f;
    o.z = p2 > 0.f ? p2 : __builtin_amdgcn_exp2f(p2 * LOG2E) - 1.f;
    o.w = p3 > 0.f ? p3 : __builtin_amdgcn_exp2f(p3 * LOG2E) - 1.f;
    *(float4*)&out[(size_t)bi * 64 + o4] = o;
}

// ---------------------------------------------------------------------------
extern "C" void kernel_launch(void* const* d_in, const int* in_sizes, int n_in,
                              void* d_out, int out_size, void* d_ws, size_t ws_size,
                              hipStream_t stream) {
    const float* x  = (const float*)d_in[0];
    const int* adj  = (const int*)d_in[1];
    const float* W  = (const float*)d_in[2];
    const float* a  = (const float*)d_in[3];
    float* out = (float*)d_out;
    char* ws = (char*)d_ws;

    // workspace layout
    u16* h_t   = (u16*)ws;                         // 2 MB
    u32* maskt = (u32*)(ws + (2 << 20));           // 2 MB
    float* s1p = (float*)(ws + (4 << 20));         // 64 KB
    float* s2p = s1p + 16384;                      // 64 KB
    float* lp  = s2p + 16384;                      // S*256 KB
    size_t base = (4u << 20) + 2 * 65536;
    int S = 4;                                     // k2 j-split: 1024 WGs = 4 WGs/CU
    while (S > 1 && base + (size_t)S * (262144 + 4194304) + 65536 > ws_size) S >>= 1;
    float* part = (float*)(ws + base + (size_t)S * 262144);   // S*4 MB
    u16* wtp = (u16*)(ws + base + (size_t)S * 262144 + (size_t)S * 4194304);  // 64 KB
    // k1 K-split partials alias the part buffer (free until k2 writes it)
    const int KS = 2;                              // k1 k-split: 512 WGs = 2 waves/SIMD

    pack_mask_kernel<<<2048, 256, 0, stream>>>(adj, maskt);
    wt_prep<<<32, 256, 0, stream>>>(W, wtp);
    k1_mfma<<<dim3(64, 4, KS), 256, 0, stream>>>(x, wtp, part);
    k1c_fin<KS><<<dim3(64, 4), 256, 0, stream>>>(part, a, h_t, s1p, s2p);
    if (S == 4)      k2_attn<32><<<dim3(64, 4, 4), 256, 0, stream>>>(h_t, maskt, s1p, s2p, part, lp);
    else if (S == 2) k2_attn<64><<<dim3(64, 4, 2), 256, 0, stream>>>(h_t, maskt, s1p, s2p, part, lp);
    else             k2_attn<128><<<dim3(64, 4, 1), 256, 0, stream>>>(h_t, maskt, s1p, s2p, part, lp);
    if (S == 4)      k3_fin<4><<<1024, 256, 0, stream>>>(part, lp, out);
    else if (S == 2) k3_fin<2><<<1024, 256, 0, stream>>>(part, lp, out);
    else             k3_fin<1><<<1024, 256, 0, stream>>>(part, lp, out);
}

// Round 9
// 169.869 us; speedup vs baseline: 1.3660x; 1.1933x over previous
//
#include <hip/hip_runtime.h>

#define LOG2E 1.4426950408889634f

typedef __attribute__((ext_vector_type(8))) short short8;
typedef __attribute__((ext_vector_type(4))) float f32x4;
using u32 = unsigned int;
using u16 = unsigned short;
using u64 = unsigned long long;

// ---------------------------------------------------------------------------
// Kernel P: pack adj (4096x4096 int32 0/1) into transposed bitmask.
// ---------------------------------------------------------------------------
__global__ __launch_bounds__(256) void pack_mask_kernel(const int* __restrict__ adj,
                                                        u32* __restrict__ mask_t) {
    const int wid = (blockIdx.x * 256 + threadIdx.x) >> 6;
    const int lane = threadIdx.x & 63;
    for (int t = wid; t < 65536; t += 8192) {          // task = (row, 4-chunk group)
        const int r = t >> 4, c4 = t & 15;
        const int* base = adj + (size_t)r * 4096 + c4 * 256 + lane;
        int v0 = __builtin_nontemporal_load(base);
        int v1 = __builtin_nontemporal_load(base + 64);
        int v2 = __builtin_nontemporal_load(base + 128);
        int v3 = __builtin_nontemporal_load(base + 192);
        u64 b0 = __ballot(v0 > 0);
        u64 b1 = __ballot(v1 > 0);
        u64 b2 = __ballot(v2 > 0);
        u64 b3 = __ballot(v3 > 0);
        if (lane < 8) {                                 // lane k stores word-col c4*8+k
            u64 bv = (lane & 4) ? ((lane & 2) ? b3 : b2) : ((lane & 2) ? b1 : b0);
            u32 w = (u32)(bv >> ((lane & 1) << 5));
            mask_t[(size_t)(c4 * 8 + lane) * 4096 + r] = w;
        }
    }
}

// ---------------------------------------------------------------------------
// Kernel W: transpose W (512x64 fp32) -> Wt[64][512] bf16 (round-half-up).
// ---------------------------------------------------------------------------
__global__ __launch_bounds__(256) void wt_prep(const float* __restrict__ W,
                                               u16* __restrict__ wt) {
    int t = blockIdx.x * 256 + threadIdx.x;            // 8192 threads
    int n = t >> 7, k4 = (t & 127) << 2;
    u32 c0 = __float_as_uint(W[(size_t)(k4 + 0) * 64 + n]) + 0x8000u;
    u32 c1 = __float_as_uint(W[(size_t)(k4 + 1) * 64 + n]) + 0x8000u;
    u32 c2 = __float_as_uint(W[(size_t)(k4 + 2) * 64 + n]) + 0x8000u;
    u32 c3 = __float_as_uint(W[(size_t)(k4 + 3) * 64 + n]) + 0x8000u;
    uint2 o;
    o.x = (c0 >> 16) | (c1 & 0xffff0000u);
    o.y = (c2 >> 16) | (c3 & 0xffff0000u);
    *(uint2*)(wt + (size_t)n * 512 + k4) = o;
}

// ---------------------------------------------------------------------------
// Kernel 1: h-partial = x @ W via bf16 MFMA, barrier-free, no LDS (r8 WIN).
// ---------------------------------------------------------------------------
__global__ __launch_bounds__(256) void k1_mfma(const float* __restrict__ x,
                                               const u16* __restrict__ wt,
                                               float* __restrict__ ph) {
    const int rt = blockIdx.x, b = blockIdx.y, kz = blockIdx.z;
    const int tid = threadIdx.x, wave = tid >> 6, lane = tid & 63;
    const int m = lane & 15, quad = lane >> 4;
    const int row = rt * 64 + wave * 16 + m;
    const float* xb = x + ((size_t)b * 4096 + row) * 512 + kz * 256 + quad * 8;
    const u16* wb = wt + (size_t)m * 512 + kz * 256 + quad * 8;

    f32x4 acc[4];
#pragma unroll
    for (int ot = 0; ot < 4; ot++) acc[ot] = (f32x4){0.f, 0.f, 0.f, 0.f};

    union BU { uint4 q; short8 v; };
    float4 ax[2][2];
    BU bw[2][4];
#pragma unroll
    for (int s = 0; s < 2; s++) {          // preload k-steps 0,1
        ax[s][0] = *(const float4*)(xb + s * 32);
        ax[s][1] = *(const float4*)(xb + s * 32 + 4);
#pragma unroll
        for (int ot = 0; ot < 4; ot++)
            bw[s][ot].q = *(const uint4*)(wb + (size_t)ot * 16 * 512 + s * 32);
    }
#pragma unroll
    for (int s = 0; s < 8; s++) {          // K=256 in 8 steps of 32
        const int cur = s & 1;
        union { u32 u[4]; short8 v; } af;
        const float* a0 = (const float*)&ax[cur][0];
#pragma unroll
        for (int p = 0; p < 4; p++) {      // round-half-up bf16 pack (lo=k even)
            u32 lo = __float_as_uint(a0[2 * p]) + 0x8000u;
            u32 hi = __float_as_uint(a0[2 * p + 1]) + 0x8000u;
            af.u[p] = __builtin_amdgcn_perm(hi, lo, 0x07060302u);
        }
#pragma unroll
        for (int ot = 0; ot < 4; ot++)
            acc[ot] = __builtin_amdgcn_mfma_f32_16x16x32_bf16(af.v, bw[cur][ot].v,
                                                              acc[ot], 0, 0, 0);
        if (s + 2 < 8) {                   // prefetch after consumption
            ax[cur][0] = *(const float4*)(xb + (s + 2) * 32);
            ax[cur][1] = *(const float4*)(xb + (s + 2) * 32 + 4);
#pragma unroll
            for (int ot = 0; ot < 4; ot++)
                bw[cur][ot].q =
                    *(const uint4*)(wb + (size_t)ot * 16 * 512 + (s + 2) * 32);
        }
    }
    float* pb = ph + (((size_t)(kz * 4 + b) * 4096) + rt * 64 + wave * 16) * 64;
#pragma unroll
    for (int ot = 0; ot < 4; ot++)
#pragma unroll
        for (int r = 0; r < 4; r++)
            pb[(quad * 4 + r) * 64 + ot * 16 + m] = acc[ot][r];
}

// ---------------------------------------------------------------------------
// Kernel 1c: sum K-split partials; epilogue: s1/s2 (pre-scaled), h^T bf16.
// ---------------------------------------------------------------------------
template <int KS>
__global__ __launch_bounds__(256) void k1c_fin(const float* __restrict__ ph,
                                               const float* __restrict__ a,
                                               u16* __restrict__ h_t,
                                               float* __restrict__ s1p,
                                               float* __restrict__ s2p) {
    const int b = blockIdx.y, rt = blockIdx.x;
    const int tid = threadIdx.x;
    const int rg = tid >> 4, cg = tid & 15;
    const int r0 = rg * 4, c0 = cg * 4;

    float4 v[KS][4];
#pragma unroll
    for (int s = 0; s < KS; s++) {
        const float* pb = ph + (((size_t)(s * 4 + b) * 4096) + rt * 64) * 64;
#pragma unroll
        for (int rr = 0; rr < 4; rr++)
            v[s][rr] = *(const float4*)&pb[(size_t)(r0 + rr) * 64 + c0];
    }
    float acc[4][4];
#pragma unroll
    for (int rr = 0; rr < 4; rr++) {
        acc[rr][0] = acc[rr][1] = acc[rr][2] = acc[rr][3] = 0.f;
#pragma unroll
        for (int s = 0; s < KS; s++) {
            acc[rr][0] += v[s][rr].x; acc[rr][1] += v[s][rr].y;
            acc[rr][2] += v[s][rr].z; acc[rr][3] += v[s][rr].w;
        }
    }
    float s1v[4], s2v[4];
#pragma unroll
    for (int rr = 0; rr < 4; rr++) { s1v[rr] = 0.f; s2v[rr] = 0.f; }
#pragma unroll
    for (int cc = 0; cc < 4; cc++) {
        float a1 = a[c0 + cc], a2 = a[64 + c0 + cc];
#pragma unroll
        for (int rr = 0; rr < 4; rr++) {
            s1v[rr] = fmaf(acc[rr][cc], a1, s1v[rr]);
            s2v[rr] = fmaf(acc[rr][cc], a2, s2v[rr]);
        }
    }
#pragma unroll
    for (int d = 1; d < 16; d <<= 1) {
#pragma unroll
        for (int rr = 0; rr < 4; rr++) {
            s1v[rr] += __shfl_xor(s1v[rr], d);
            s2v[rr] += __shfl_xor(s2v[rr], d);
        }
    }
    if (cg == 0) {
#pragma unroll
        for (int rr = 0; rr < 4; rr++) {
            int row = rt * 64 + r0 + rr;
            s1p[b * 4096 + row] = s1v[rr] * LOG2E;
            s2p[b * 4096 + row] = s2v[rr] * LOG2E;
        }
    }
#pragma unroll
    for (int cc = 0; cc < 4; cc++) {
        u32 b0 = __float_as_uint(acc[0][cc]) + 0x8000u;
        u32 b1 = __float_as_uint(acc[1][cc]) + 0x8000u;
        u32 b2 = __float_as_uint(acc[2][cc]) + 0x8000u;
        u32 b3 = __float_as_uint(acc[3][cc]) + 0x8000u;
        uint2 u;
        u.x = (b0 >> 16) | (b1 & 0xffff0000u);
        u.y = (b2 >> 16) | (b3 & 0xffff0000u);
        *(uint2*)(h_t + ((size_t)(b * 64 + c0 + cc)) * 4096 + rt * 64 + r0) = u;
    }
}

// ---------------------------------------------------------------------------
// Kernel 2: fused masked-softmax-numerator GEMM. r2's LDS-staged structure
// (fastest measured: 50.4 us) + three fixes:
//  - rolling 4-deep mask window (r2 loaded mask w/ immediate use = ~200 cyc
//    serial stall/step); consume-before-overwrite (r5 lesson).
//  - double-buffered LDS B-tile -> 1 barrier per 64-j tile instead of 2.
//  - denominator via 5th MFMA with B=ones: deletes 16 lsum adds/step and sums
//    exactly the truncated-bf16 numerator weights (truncation bias cancels);
//    pack becomes a single v_perm truncate.
// S=8 -> 2048 WGs; LDS 18 KB/WG -> up to 8 WGs/CU.
// ---------------------------------------------------------------------------
template <int NSTEP>
__global__ __launch_bounds__(256, 4) void k2_attn(const u16* __restrict__ h_t,
                                                  const u32* __restrict__ mask_t,
                                                  const float* __restrict__ s1p,
                                                  const float* __restrict__ s2p,
                                                  float* __restrict__ part,
                                                  float* __restrict__ lp) {
    constexpr int JSEG = NSTEP * 32;
    constexpr int T = NSTEP / 2;           // 64-j tiles
    __shared__ u16 hB[2][64 * 64];         // double buffer, xor-swizzled
    __shared__ float s2l[JSEG];
    const int b = blockIdx.y, seg = blockIdx.z, rb = blockIdx.x;
    const int tid = threadIdx.x, wave = tid >> 6, lane = tid & 63;
    const int m = lane & 15, quad = lane >> 4;
    const int row = rb * 64 + wave * 16 + m;
    const int jstart = seg * JSEG;
    const float t1 = s1p[b * 4096 + row];
    const u16* hsrc = h_t + (size_t)b * 64 * 4096 + jstart;
    const u32* mrow = mask_t + (size_t)(jstart >> 5) * 4096 + row;

    for (int t = tid; t < (JSEG >> 2); t += 256)
        ((float4*)s2l)[t] = ((const float4*)(s2p + b * 4096 + jstart))[t];

    f32x4 acc[4], accd;
#pragma unroll
    for (int ot = 0; ot < 4; ot++) acc[ot] = (f32x4){0.f, 0.f, 0.f, 0.f};
    accd = (f32x4){0.f, 0.f, 0.f, 0.f};

    u32 mw[4];
#pragma unroll
    for (int s = 0; s < 4; s++) mw[s] = mrow[(size_t)s * 4096];
    union { u32 u[4]; short8 v; } ones;
#pragma unroll
    for (int p = 0; p < 4; p++) ones.u[p] = 0x3F803F80u;   // bf16 1.0 pairs

    const int cj = tid & 7;                // 16B chunk column (8 j's)
    const int ow = tid >> 3;               // rows ow, ow+32
    uint4 pf[2];
    pf[0] = *(const uint4*)(hsrc + (size_t)ow * 4096 + (cj << 3));
    pf[1] = *(const uint4*)(hsrc + (size_t)(ow + 32) * 4096 + (cj << 3));
    *(uint4*)(hB[0] + (size_t)ow * 64 + ((cj ^ (ow & 7)) << 3)) = pf[0];
    *(uint4*)(hB[0] + (size_t)(ow + 32) * 64 + ((cj ^ ((ow + 32) & 7)) << 3)) = pf[1];
    __syncthreads();                       // tile 0 + s2l ready

    for (int jt = 0; jt < T; jt++) {
        const int cb = jt & 1;
        if (jt + 1 < T) {                  // global prefetch of next 64-j tile
            pf[0] = *(const uint4*)(hsrc + (size_t)ow * 4096 + (jt + 1) * 64 + (cj << 3));
            pf[1] = *(const uint4*)(hsrc + (size_t)(ow + 32) * 4096 + (jt + 1) * 64 + (cj << 3));
        }
#pragma unroll
        for (int ks = 0; ks < 2; ks++) {
            const int s = jt * 2 + ks;
            // consume BEFORE the distance-4 prefetch overwrites the slot
            const u32 mws = mw[s & 3] >> (quad * 8);
            if (s + 4 < NSTEP) mw[(s + 4) & 3] = mrow[(size_t)(s + 4) * 4096];

            const float4 sa = *(const float4*)&s2l[s * 32 + quad * 8];
            const float4 sb = *(const float4*)&s2l[s * 32 + quad * 8 + 4];
            const float sv[8] = {sa.x, sa.y, sa.z, sa.w, sb.x, sb.y, sb.z, sb.w};
            union { u32 u[4]; short8 v; } af;
#pragma unroll
            for (int p = 0; p < 4; p++) {
                float t0 = t1 + sv[2 * p];
                float u0 = fmaxf(t0, 0.2f * t0);                     // leaky-relu (log2 dom)
                float w0 = __builtin_amdgcn_exp2f(u0);
                u32 m0 = (u32)(((int)(mws << (31 - 2 * p))) >> 31);  // bit -> all-ones/0
                u32 w0u = __float_as_uint(w0) & m0;                  // masked -> +0.0
                float t2 = t1 + sv[2 * p + 1];
                float u2 = fmaxf(t2, 0.2f * t2);
                float w1 = __builtin_amdgcn_exp2f(u2);
                u32 m1 = (u32)(((int)(mws << (30 - 2 * p))) >> 31);
                u32 w1u = __float_as_uint(w1) & m1;
                af.u[p] = __builtin_amdgcn_perm(w1u, w0u, 0x07060302u);  // bf16 truncate
            }
            const int jc = ks * 4 + quad;
#pragma unroll
            for (int ot = 0; ot < 4; ot++) {
                const int o = ot * 16 + m;
                short8 bfv = *(const short8*)(hB[cb] + (size_t)o * 64 + ((jc ^ (o & 7)) << 3));
                acc[ot] = __builtin_amdgcn_mfma_f32_16x16x32_bf16(af.v, bfv, acc[ot], 0, 0, 0);
            }
            accd = __builtin_amdgcn_mfma_f32_16x16x32_bf16(af.v, ones.v, accd, 0, 0, 0);
        }
        if (jt + 1 < T) {                  // stage next tile into the idle buffer
            const int nb = cb ^ 1;
            *(uint4*)(hB[nb] + (size_t)ow * 64 + ((cj ^ (ow & 7)) << 3)) = pf[0];
            *(uint4*)(hB[nb] + (size_t)(ow + 32) * 64 + ((cj ^ ((ow + 32) & 7)) << 3)) = pf[1];
        }
        __syncthreads();
    }
    // C/D layout: col=lane&15, row=quad*4+reg
    float* pb = part + (((size_t)(seg * 4 + b) * 4096) + rb * 64 + wave * 16) * 64;
#pragma unroll
    for (int ot = 0; ot < 4; ot++)
#pragma unroll
        for (int r = 0; r < 4; r++)
            pb[(quad * 4 + r) * 64 + ot * 16 + m] = acc[ot][r];
    if (m == 0) {                          // accd cols all equal; rows quad*4+r
        float* lpb = lp + (size_t)(seg * 4 + b) * 4096 + rb * 64 + wave * 16 + quad * 4;
#pragma unroll
        for (int r = 0; r < 4; r++) lpb[r] = accd[r];
    }
}

// ---------------------------------------------------------------------------
// Kernel 3: combine j-split partials, normalize, elu (scalar denom per row).
// ---------------------------------------------------------------------------
template <int S>
__global__ __launch_bounds__(256) void k3_fin(const float* __restrict__ part,
                                              const float* __restrict__ lp,
                                              float* __restrict__ out) {
    int idx = blockIdx.x * 256 + threadIdx.x;    // 262144 = 4*4096*16
    int o4 = (idx & 15) << 2;
    int bi = idx >> 4;
    float4 pv[S];
    float lv[S];
#pragma unroll
    for (int s = 0; s < S; s++) {
        pv[s] = *(const float4*)&part[((size_t)s * 16384 + bi) * 64 + o4];
        lv[s] = lp[(size_t)s * 16384 + bi];
    }
    float p0 = 0.f, p1 = 0.f, p2 = 0.f, p3 = 0.f, l = 0.f;
#pragma unroll
    for (int s = 0; s < S; s++) {
        p0 += pv[s].x; p1 += pv[s].y; p2 += pv[s].z; p3 += pv[s].w;
        l += lv[s];
    }
    float rl = 1.f / l;
    p0 *= rl; p1 *= rl; p2 *= rl; p3 *= rl;
    float4 o;
    o.x = p0 > 0.f ? p0 : __builtin_amdgcn_exp2f(p0 * LOG2E) - 1.f;
    o.y = p1 > 0.f ? p1 : __builtin_amdgcn_exp2f(p1 * LOG2E) - 1.f;
    o.z = p2 > 0.f ? p2 : __builtin_amdgcn_exp2f(p2 * LOG2E) - 1.f;
    o.w = p3 > 0.f ? p3 : __builtin_amdgcn_exp2f(p3 * LOG2E) - 1.f;
    *(float4*)&out[(size_t)bi * 64 + o4] = o;
}

// ---------------------------------------------------------------------------
extern "C" void kernel_launch(void* const* d_in, const int* in_sizes, int n_in,
                              void* d_out, int out_size, void* d_ws, size_t ws_size,
                              hipStream_t stream) {
    const float* x  = (const float*)d_in[0];
    const int* adj  = (const int*)d_in[1];
    const float* W  = (const float*)d_in[2];
    const float* a  = (const float*)d_in[3];
    float* out = (float*)d_out;
    char* ws = (char*)d_ws;

    // workspace layout
    u16* h_t   = (u16*)ws;                         // 2 MB
    u32* maskt = (u32*)(ws + (2 << 20));           // 2 MB
    float* s1p = (float*)(ws + (4 << 20));         // 64 KB
    float* s2p = s1p + 16384;                      // 64 KB
    float* lp  = s2p + 16384;                      // S*64 KB (1 float/row)
    size_t base = (4u << 20) + 2 * 65536;
    int S = 8;                                     // k2 j-split: 2048 WGs
    while (S > 1 && base + (size_t)S * (65536 + 4194304) + 65536 > ws_size) S >>= 1;
    float* part = (float*)(ws + base + (size_t)S * 65536);    // S*4 MB
    u16* wtp = (u16*)(ws + base + (size_t)S * 65536 + (size_t)S * 4194304);  // 64 KB
    // k1 K-split partials alias the part buffer (free until k2 writes it)
    const int KS = 2;                              // k1 k-split: 512 WGs

    pack_mask_kernel<<<2048, 256, 0, stream>>>(adj, maskt);
    wt_prep<<<32, 256, 0, stream>>>(W, wtp);
    k1_mfma<<<dim3(64, 4, KS), 256, 0, stream>>>(x, wtp, part);
    k1c_fin<KS><<<dim3(64, 4), 256, 0, stream>>>(part, a, h_t, s1p, s2p);
    if (S == 8)      k2_attn<16><<<dim3(64, 4, 8), 256, 0, stream>>>(h_t, maskt, s1p, s2p, part, lp);
    else if (S == 4) k2_attn<32><<<dim3(64, 4, 4), 256, 0, stream>>>(h_t, maskt, s1p, s2p, part, lp);
    else if (S == 2) k2_attn<64><<<dim3(64, 4, 2), 256, 0, stream>>>(h_t, maskt, s1p, s2p, part, lp);
    else             k2_attn<128><<<dim3(64, 4, 1), 256, 0, stream>>>(h_t, maskt, s1p, s2p, part, lp);
    if (S == 8)      k3_fin<8><<<1024, 256, 0, stream>>>(part, lp, out);
    else if (S == 4) k3_fin<4><<<1024, 256, 0, stream>>>(part, lp, out);
    else if (S == 2) k3_fin<2><<<1024, 256, 0, stream>>>(part, lp, out);
    else             k3_fin<1><<<1024, 256, 0, stream>>>(part, lp, out);
}

// Round 10
// 166.801 us; speedup vs baseline: 1.3911x; 1.0184x over previous
//
#include <hip/hip_runtime.h>

#define LOG2E 1.4426950408889634f

typedef __attribute__((ext_vector_type(8))) short short8;
typedef __attribute__((ext_vector_type(4))) float f32x4;
using u32 = unsigned int;
using u16 = unsigned short;
using u64 = unsigned long long;

// ---------------------------------------------------------------------------
// Kernel P: pack adj (4096x4096 int32 0/1) into transposed bitmask.
// ---------------------------------------------------------------------------
__global__ __launch_bounds__(256) void pack_mask_kernel(const int* __restrict__ adj,
                                                        u32* __restrict__ mask_t) {
    const int wid = (blockIdx.x * 256 + threadIdx.x) >> 6;
    const int lane = threadIdx.x & 63;
    for (int t = wid; t < 65536; t += 8192) {          // task = (row, 4-chunk group)
        const int r = t >> 4, c4 = t & 15;
        const int* base = adj + (size_t)r * 4096 + c4 * 256 + lane;
        int v0 = __builtin_nontemporal_load(base);
        int v1 = __builtin_nontemporal_load(base + 64);
        int v2 = __builtin_nontemporal_load(base + 128);
        int v3 = __builtin_nontemporal_load(base + 192);
        u64 b0 = __ballot(v0 > 0);
        u64 b1 = __ballot(v1 > 0);
        u64 b2 = __ballot(v2 > 0);
        u64 b3 = __ballot(v3 > 0);
        if (lane < 8) {                                 // lane k stores word-col c4*8+k
            u64 bv = (lane & 4) ? ((lane & 2) ? b3 : b2) : ((lane & 2) ? b1 : b0);
            u32 w = (u32)(bv >> ((lane & 1) << 5));
            mask_t[(size_t)(c4 * 8 + lane) * 4096 + r] = w;
        }
    }
}

// ---------------------------------------------------------------------------
// Kernel W: transpose W (512x64 fp32) -> Wt[64][512] bf16 (round-half-up).
// ---------------------------------------------------------------------------
__global__ __launch_bounds__(256) void wt_prep(const float* __restrict__ W,
                                               u16* __restrict__ wt) {
    int t = blockIdx.x * 256 + threadIdx.x;            // 8192 threads
    int n = t >> 7, k4 = (t & 127) << 2;
    u32 c0 = __float_as_uint(W[(size_t)(k4 + 0) * 64 + n]) + 0x8000u;
    u32 c1 = __float_as_uint(W[(size_t)(k4 + 1) * 64 + n]) + 0x8000u;
    u32 c2 = __float_as_uint(W[(size_t)(k4 + 2) * 64 + n]) + 0x8000u;
    u32 c3 = __float_as_uint(W[(size_t)(k4 + 3) * 64 + n]) + 0x8000u;
    uint2 o;
    o.x = (c0 >> 16) | (c1 & 0xffff0000u);
    o.y = (c2 >> 16) | (c3 & 0xffff0000u);
    *(uint2*)(wt + (size_t)n * 512 + k4) = o;
}

// ---------------------------------------------------------------------------
// Kernel 1f: h = x @ W via bf16 MFMA with IN-WORKGROUP K-split + fused
// epilogue (replaces k1_mfma + k1c_fin: kills the 8 MB partial round-trip,
// the extra launch, and k1c's 1-WG/CU latency tail).
// WG = 512 threads (8 waves): wave w = (g = w&3 row-group, kz = w>>2 K-half).
// Waves kz=1 dump acc tiles to LDS (stride-65 pad -> 2-way conflicts = free),
// one barrier, waves kz=0 add + epilogue (s1/s2 shuffle-reduce, h^T bf16).
// Grid (64,4) x 512 = 2048 waves = 2/SIMD, same as r8's k1+KS=2.
// ---------------------------------------------------------------------------
__global__ __launch_bounds__(512) void k1f(const float* __restrict__ x,
                                           const u16* __restrict__ wt,
                                           const float* __restrict__ a,
                                           u16* __restrict__ h_t,
                                           float* __restrict__ s1p,
                                           float* __restrict__ s2p) {
    __shared__ float red[4][16][65];       // 16.6 KB
    const int rt = blockIdx.x, b = blockIdx.y;
    const int tid = threadIdx.x, wave = tid >> 6, lane = tid & 63;
    const int g = wave & 3, kz = wave >> 2;
    const int m = lane & 15, quad = lane >> 4;
    const int row = rt * 64 + g * 16 + m;
    const float* xb = x + ((size_t)b * 4096 + row) * 512 + kz * 256 + quad * 8;
    const u16* wb = wt + (size_t)m * 512 + kz * 256 + quad * 8;

    f32x4 acc[4];
#pragma unroll
    for (int ot = 0; ot < 4; ot++) acc[ot] = (f32x4){0.f, 0.f, 0.f, 0.f};

    union BU { uint4 q; short8 v; };
    float4 ax[2][2];
    BU bw[2][4];
#pragma unroll
    for (int s = 0; s < 2; s++) {          // preload k-steps 0,1
        ax[s][0] = *(const float4*)(xb + s * 32);
        ax[s][1] = *(const float4*)(xb + s * 32 + 4);
#pragma unroll
        for (int ot = 0; ot < 4; ot++)
            bw[s][ot].q = *(const uint4*)(wb + (size_t)ot * 16 * 512 + s * 32);
    }
#pragma unroll
    for (int s = 0; s < 8; s++) {          // K=256 in 8 steps of 32
        const int cur = s & 1;
        union { u32 u[4]; short8 v; } af;
        const float* a0 = (const float*)&ax[cur][0];
#pragma unroll
        for (int p = 0; p < 4; p++) {      // round-half-up bf16 pack (lo=k even)
            u32 lo = __float_as_uint(a0[2 * p]) + 0x8000u;
            u32 hi = __float_as_uint(a0[2 * p + 1]) + 0x8000u;
            af.u[p] = __builtin_amdgcn_perm(hi, lo, 0x07060302u);
        }
#pragma unroll
        for (int ot = 0; ot < 4; ot++)
            acc[ot] = __builtin_amdgcn_mfma_f32_16x16x32_bf16(af.v, bw[cur][ot].v,
                                                              acc[ot], 0, 0, 0);
        if (s + 2 < 8) {                   // prefetch after consumption
            ax[cur][0] = *(const float4*)(xb + (s + 2) * 32);
            ax[cur][1] = *(const float4*)(xb + (s + 2) * 32 + 4);
#pragma unroll
            for (int ot = 0; ot < 4; ot++)
                bw[cur][ot].q =
                    *(const uint4*)(wb + (size_t)ot * 16 * 512 + (s + 2) * 32);
        }
    }
    // C/D layout: col = ot*16 + m, row(within 16) = quad*4 + r
    if (kz) {
#pragma unroll
        for (int ot = 0; ot < 4; ot++)
#pragma unroll
            for (int r = 0; r < 4; r++)
                red[g][quad * 4 + r][ot * 16 + m] = acc[ot][r];
    }
    __syncthreads();
    if (kz) return;
#pragma unroll
    for (int ot = 0; ot < 4; ot++)
#pragma unroll
        for (int r = 0; r < 4; r++)
            acc[ot][r] += red[g][quad * 4 + r][ot * 16 + m];

    // epilogue: s1/s2 (pre-scaled by log2e) via within-quad shuffle reduce
    float a1v[4], a2v[4];
#pragma unroll
    for (int ot = 0; ot < 4; ot++) {
        a1v[ot] = a[ot * 16 + m];
        a2v[ot] = a[64 + ot * 16 + m];
    }
    float s1r[4], s2r[4];
#pragma unroll
    for (int r = 0; r < 4; r++) {
        s1r[r] = 0.f; s2r[r] = 0.f;
#pragma unroll
        for (int ot = 0; ot < 4; ot++) {
            s1r[r] = fmaf(acc[ot][r], a1v[ot], s1r[r]);
            s2r[r] = fmaf(acc[ot][r], a2v[ot], s2r[r]);
        }
    }
#pragma unroll
    for (int d = 1; d < 16; d <<= 1) {
#pragma unroll
        for (int r = 0; r < 4; r++) {
            s1r[r] += __shfl_xor(s1r[r], d);
            s2r[r] += __shfl_xor(s2r[r], d);
        }
    }
    if (m == 0) {
#pragma unroll
        for (int r = 0; r < 4; r++) {
            int rr = rt * 64 + g * 16 + quad * 4 + r;
            s1p[b * 4096 + rr] = s1r[r] * LOG2E;
            s2p[b * 4096 + rr] = s2r[r] * LOG2E;
        }
    }
    // h^T bf16 (round-half-up): per ot, pack 4 consecutive rows of one col
#pragma unroll
    for (int ot = 0; ot < 4; ot++) {
        u32 b0 = __float_as_uint(acc[ot][0]) + 0x8000u;
        u32 b1 = __float_as_uint(acc[ot][1]) + 0x8000u;
        u32 b2 = __float_as_uint(acc[ot][2]) + 0x8000u;
        u32 b3 = __float_as_uint(acc[ot][3]) + 0x8000u;
        uint2 u;
        u.x = (b0 >> 16) | (b1 & 0xffff0000u);
        u.y = (b2 >> 16) | (b3 & 0xffff0000u);
        *(uint2*)(h_t + ((size_t)(b * 64 + ot * 16 + m)) * 4096
                  + rt * 64 + g * 16 + quad * 4) = u;
    }
}

// ---------------------------------------------------------------------------
// Kernel 2: fused masked-softmax-numerator GEMM (r9 WIN structure, unchanged;
// now launched with S=4 to halve part/lp traffic).
// ---------------------------------------------------------------------------
template <int NSTEP>
__global__ __launch_bounds__(256, 4) void k2_attn(const u16* __restrict__ h_t,
                                                  const u32* __restrict__ mask_t,
                                                  const float* __restrict__ s1p,
                                                  const float* __restrict__ s2p,
                                                  float* __restrict__ part,
                                                  float* __restrict__ lp) {
    constexpr int JSEG = NSTEP * 32;
    constexpr int T = NSTEP / 2;           // 64-j tiles
    __shared__ u16 hB[2][64 * 64];         // double buffer, xor-swizzled
    __shared__ float s2l[JSEG];
    const int b = blockIdx.y, seg = blockIdx.z, rb = blockIdx.x;
    const int tid = threadIdx.x, wave = tid >> 6, lane = tid & 63;
    const int m = lane & 15, quad = lane >> 4;
    const int row = rb * 64 + wave * 16 + m;
    const int jstart = seg * JSEG;
    const float t1 = s1p[b * 4096 + row];
    const u16* hsrc = h_t + (size_t)b * 64 * 4096 + jstart;
    const u32* mrow = mask_t + (size_t)(jstart >> 5) * 4096 + row;

    for (int t = tid; t < (JSEG >> 2); t += 256)
        ((float4*)s2l)[t] = ((const float4*)(s2p + b * 4096 + jstart))[t];

    f32x4 acc[4], accd;
#pragma unroll
    for (int ot = 0; ot < 4; ot++) acc[ot] = (f32x4){0.f, 0.f, 0.f, 0.f};
    accd = (f32x4){0.f, 0.f, 0.f, 0.f};

    u32 mw[4];
#pragma unroll
    for (int s = 0; s < 4; s++) mw[s] = mrow[(size_t)s * 4096];
    union { u32 u[4]; short8 v; } ones;
#pragma unroll
    for (int p = 0; p < 4; p++) ones.u[p] = 0x3F803F80u;   // bf16 1.0 pairs

    const int cj = tid & 7;                // 16B chunk column (8 j's)
    const int ow = tid >> 3;               // rows ow, ow+32
    uint4 pf[2];
    pf[0] = *(const uint4*)(hsrc + (size_t)ow * 4096 + (cj << 3));
    pf[1] = *(const uint4*)(hsrc + (size_t)(ow + 32) * 4096 + (cj << 3));
    *(uint4*)(hB[0] + (size_t)ow * 64 + ((cj ^ (ow & 7)) << 3)) = pf[0];
    *(uint4*)(hB[0] + (size_t)(ow + 32) * 64 + ((cj ^ ((ow + 32) & 7)) << 3)) = pf[1];
    __syncthreads();                       // tile 0 + s2l ready

    for (int jt = 0; jt < T; jt++) {
        const int cb = jt & 1;
        if (jt + 1 < T) {                  // global prefetch of next 64-j tile
            pf[0] = *(const uint4*)(hsrc + (size_t)ow * 4096 + (jt + 1) * 64 + (cj << 3));
            pf[1] = *(const uint4*)(hsrc + (size_t)(ow + 32) * 4096 + (jt + 1) * 64 + (cj << 3));
        }
#pragma unroll
        for (int ks = 0; ks < 2; ks++) {
            const int s = jt * 2 + ks;
            // consume BEFORE the distance-4 prefetch overwrites the slot
            const u32 mws = mw[s & 3] >> (quad * 8);
            if (s + 4 < NSTEP) mw[(s + 4) & 3] = mrow[(size_t)(s + 4) * 4096];

            const float4 sa = *(const float4*)&s2l[s * 32 + quad * 8];
            const float4 sb = *(const float4*)&s2l[s * 32 + quad * 8 + 4];
            const float sv[8] = {sa.x, sa.y, sa.z, sa.w, sb.x, sb.y, sb.z, sb.w};
            union { u32 u[4]; short8 v; } af;
#pragma unroll
            for (int p = 0; p < 4; p++) {
                float t0 = t1 + sv[2 * p];
                float u0 = fmaxf(t0, 0.2f * t0);                     // leaky-relu (log2 dom)
                float w0 = __builtin_amdgcn_exp2f(u0);
                u32 m0 = (u32)(((int)(mws << (31 - 2 * p))) >> 31);  // bit -> all-ones/0
                u32 w0u = __float_as_uint(w0) & m0;                  // masked -> +0.0
                float t2 = t1 + sv[2 * p + 1];
                float u2 = fmaxf(t2, 0.2f * t2);
                float w1 = __builtin_amdgcn_exp2f(u2);
                u32 m1 = (u32)(((int)(mws << (30 - 2 * p))) >> 31);
                u32 w1u = __float_as_uint(w1) & m1;
                af.u[p] = __builtin_amdgcn_perm(w1u, w0u, 0x07060302u);  // bf16 truncate
            }
            const int jc = ks * 4 + quad;
#pragma unroll
            for (int ot = 0; ot < 4; ot++) {
                const int o = ot * 16 + m;
                short8 bfv = *(const short8*)(hB[cb] + (size_t)o * 64 + ((jc ^ (o & 7)) << 3));
                acc[ot] = __builtin_amdgcn_mfma_f32_16x16x32_bf16(af.v, bfv, acc[ot], 0, 0, 0);
            }
            accd = __builtin_amdgcn_mfma_f32_16x16x32_bf16(af.v, ones.v, accd, 0, 0, 0);
        }
        if (jt + 1 < T) {                  // stage next tile into the idle buffer
            const int nb = cb ^ 1;
            *(uint4*)(hB[nb] + (size_t)ow * 64 + ((cj ^ (ow & 7)) << 3)) = pf[0];
            *(uint4*)(hB[nb] + (size_t)(ow + 32) * 64 + ((cj ^ ((ow + 32) & 7)) << 3)) = pf[1];
        }
        __syncthreads();
    }
    // C/D layout: col=lane&15, row=quad*4+reg
    float* pb = part + (((size_t)(seg * 4 + b) * 4096) + rb * 64 + wave * 16) * 64;
#pragma unroll
    for (int ot = 0; ot < 4; ot++)
#pragma unroll
        for (int r = 0; r < 4; r++)
            pb[(quad * 4 + r) * 64 + ot * 16 + m] = acc[ot][r];
    if (m == 0) {                          // accd cols all equal; rows quad*4+r
        float* lpb = lp + (size_t)(seg * 4 + b) * 4096 + rb * 64 + wave * 16 + quad * 4;
#pragma unroll
        for (int r = 0; r < 4; r++) lpb[r] = accd[r];
    }
}

// ---------------------------------------------------------------------------
// Kernel 3: combine j-split partials, normalize, elu (scalar denom per row).
// ---------------------------------------------------------------------------
template <int S>
__global__ __launch_bounds__(256) void k3_fin(const float* __restrict__ part,
                                              const float* __restrict__ lp,
                                              float* __restrict__ out) {
    int idx = blockIdx.x * 256 + threadIdx.x;    // 262144 = 4*4096*16
    int o4 = (idx & 15) << 2;
    int bi = idx >> 4;
    float4 pv[S];
    float lv[S];
#pragma unroll
    for (int s = 0; s < S; s++) {
        pv[s] = *(const float4*)&part[((size_t)s * 16384 + bi) * 64 + o4];
        lv[s] = lp[(size_t)s * 16384 + bi];
    }
    float p0 = 0.f, p1 = 0.f, p2 = 0.f, p3 = 0.f, l = 0.f;
#pragma unroll
    for (int s = 0; s < S; s++) {
        p0 += pv[s].x; p1 += pv[s].y; p2 += pv[s].z; p3 += pv[s].w;
        l += lv[s];
    }
    float rl = 1.f / l;
    p0 *= rl; p1 *= rl; p2 *= rl; p3 *= rl;
    float4 o;
    o.x = p0 > 0.f ? p0 : __builtin_amdgcn_exp2f(p0 * LOG2E) - 1.f;
    o.y = p1 > 0.f ? p1 : __builtin_amdgcn_exp2f(p1 * LOG2E) - 1.f;
    o.z = p2 > 0.f ? p2 : __builtin_amdgcn_exp2f(p2 * LOG2E) - 1.f;
    o.w = p3 > 0.f ? p3 : __builtin_amdgcn_exp2f(p3 * LOG2E) - 1.f;
    *(float4*)&out[(size_t)bi * 64 + o4] = o;
}

// ---------------------------------------------------------------------------
extern "C" void kernel_launch(void* const* d_in, const int* in_sizes, int n_in,
                              void* d_out, int out_size, void* d_ws, size_t ws_size,
                              hipStream_t stream) {
    const float* x  = (const float*)d_in[0];
    const int* adj  = (const int*)d_in[1];
    const float* W  = (const float*)d_in[2];
    const float* a  = (const float*)d_in[3];
    float* out = (float*)d_out;
    char* ws = (char*)d_ws;

    // workspace layout
    u16* h_t   = (u16*)ws;                         // 2 MB
    u32* maskt = (u32*)(ws + (2 << 20));           // 2 MB
    float* s1p = (float*)(ws + (4 << 20));         // 64 KB
    float* s2p = s1p + 16384;                      // 64 KB
    float* lp  = s2p + 16384;                      // S*64 KB (1 float/row)
    size_t base = (4u << 20) + 2 * 65536;
    int S = 4;                                     // k2 j-split: 1024 WGs, 1 pass
    while (S > 1 && base + (size_t)S * (65536 + 4194304) + 65536 > ws_size) S >>= 1;
    float* part = (float*)(ws + base + (size_t)S * 65536);    // S*4 MB
    u16* wtp = (u16*)(ws + base + (size_t)S * 65536 + (size_t)S * 4194304);  // 64 KB

    pack_mask_kernel<<<2048, 256, 0, stream>>>(adj, maskt);
    wt_prep<<<32, 256, 0, stream>>>(W, wtp);
    k1f<<<dim3(64, 4), 512, 0, stream>>>(x, wtp, a, h_t, s1p, s2p);
    if (S == 4)      k2_attn<32><<<dim3(64, 4, 4), 256, 0, stream>>>(h_t, maskt, s1p, s2p, part, lp);
    else if (S == 2) k2_attn<64><<<dim3(64, 4, 2), 256, 0, stream>>>(h_t, maskt, s1p, s2p, part, lp);
    else             k2_attn<128><<<dim3(64, 4, 1), 256, 0, stream>>>(h_t, maskt, s1p, s2p, part, lp);
    if (S == 4)      k3_fin<4><<<1024, 256, 0, stream>>>(part, lp, out);
    else if (S == 2) k3_fin<2><<<1024, 256, 0, stream>>>(part, lp, out);
    else             k3_fin<1><<<1024, 256, 0, stream>>>(part, lp, out);
}

// Round 11
// 160.365 us; speedup vs baseline: 1.4470x; 1.0401x over previous
//
#include <hip/hip_runtime.h>

#define LOG2E 1.4426950408889634f

typedef __attribute__((ext_vector_type(8))) short short8;
typedef __attribute__((ext_vector_type(4))) float f32x4;
using u32 = unsigned int;
using u16 = unsigned short;
using u64 = unsigned long long;

// ---------------------------------------------------------------------------
// Kernel P: pack adj -> transposed bitmask; blocks >= 2048 instead transpose
// W (512x64 fp32) -> Wt[64][512] bf16 (fused to save one launch gap).
// ---------------------------------------------------------------------------
__global__ __launch_bounds__(256) void prep_kernel(const int* __restrict__ adj,
                                                   u32* __restrict__ mask_t,
                                                   const float* __restrict__ W,
                                                   u16* __restrict__ wt) {
    if (blockIdx.x >= 2048) {                          // 32 blocks: wt_prep
        int t = (blockIdx.x - 2048) * 256 + threadIdx.x;   // 8192 threads
        int n = t >> 7, k4 = (t & 127) << 2;
        u32 c0 = __float_as_uint(W[(size_t)(k4 + 0) * 64 + n]) + 0x8000u;
        u32 c1 = __float_as_uint(W[(size_t)(k4 + 1) * 64 + n]) + 0x8000u;
        u32 c2 = __float_as_uint(W[(size_t)(k4 + 2) * 64 + n]) + 0x8000u;
        u32 c3 = __float_as_uint(W[(size_t)(k4 + 3) * 64 + n]) + 0x8000u;
        uint2 o;
        o.x = (c0 >> 16) | (c1 & 0xffff0000u);
        o.y = (c2 >> 16) | (c3 & 0xffff0000u);
        *(uint2*)(wt + (size_t)n * 512 + k4) = o;
        return;
    }
    const int wid = (blockIdx.x * 256 + threadIdx.x) >> 6;
    const int lane = threadIdx.x & 63;
    for (int t = wid; t < 65536; t += 8192) {          // task = (row, 4-chunk group)
        const int r = t >> 4, c4 = t & 15;
        const int* base = adj + (size_t)r * 4096 + c4 * 256 + lane;
        int v0 = __builtin_nontemporal_load(base);
        int v1 = __builtin_nontemporal_load(base + 64);
        int v2 = __builtin_nontemporal_load(base + 128);
        int v3 = __builtin_nontemporal_load(base + 192);
        u64 b0 = __ballot(v0 > 0);
        u64 b1 = __ballot(v1 > 0);
        u64 b2 = __ballot(v2 > 0);
        u64 b3 = __ballot(v3 > 0);
        if (lane < 8) {                                 // lane k stores word-col c4*8+k
            u64 bv = (lane & 4) ? ((lane & 2) ? b3 : b2) : ((lane & 2) ? b1 : b0);
            u32 w = (u32)(bv >> ((lane & 1) << 5));
            mask_t[(size_t)(c4 * 8 + lane) * 4096 + r] = w;
        }
    }
}

// ---------------------------------------------------------------------------
// Kernel 1f: h = x @ W via bf16 MFMA, in-WG K-split + fused epilogue (r10 WIN).
// ---------------------------------------------------------------------------
__global__ __launch_bounds__(512) void k1f(const float* __restrict__ x,
                                           const u16* __restrict__ wt,
                                           const float* __restrict__ a,
                                           u16* __restrict__ h_t,
                                           float* __restrict__ s1p,
                                           float* __restrict__ s2p) {
    __shared__ float red[4][16][65];       // 16.6 KB
    const int rt = blockIdx.x, b = blockIdx.y;
    const int tid = threadIdx.x, wave = tid >> 6, lane = tid & 63;
    const int g = wave & 3, kz = wave >> 2;
    const int m = lane & 15, quad = lane >> 4;
    const int row = rt * 64 + g * 16 + m;
    const float* xb = x + ((size_t)b * 4096 + row) * 512 + kz * 256 + quad * 8;
    const u16* wb = wt + (size_t)m * 512 + kz * 256 + quad * 8;

    f32x4 acc[4];
#pragma unroll
    for (int ot = 0; ot < 4; ot++) acc[ot] = (f32x4){0.f, 0.f, 0.f, 0.f};

    union BU { uint4 q; short8 v; };
    float4 ax[2][2];
    BU bw[2][4];
#pragma unroll
    for (int s = 0; s < 2; s++) {          // preload k-steps 0,1
        ax[s][0] = *(const float4*)(xb + s * 32);
        ax[s][1] = *(const float4*)(xb + s * 32 + 4);
#pragma unroll
        for (int ot = 0; ot < 4; ot++)
            bw[s][ot].q = *(const uint4*)(wb + (size_t)ot * 16 * 512 + s * 32);
    }
#pragma unroll
    for (int s = 0; s < 8; s++) {          // K=256 in 8 steps of 32
        const int cur = s & 1;
        union { u32 u[4]; short8 v; } af;
        const float* a0 = (const float*)&ax[cur][0];
#pragma unroll
        for (int p = 0; p < 4; p++) {      // round-half-up bf16 pack (lo=k even)
            u32 lo = __float_as_uint(a0[2 * p]) + 0x8000u;
            u32 hi = __float_as_uint(a0[2 * p + 1]) + 0x8000u;
            af.u[p] = __builtin_amdgcn_perm(hi, lo, 0x07060302u);
        }
#pragma unroll
        for (int ot = 0; ot < 4; ot++)
            acc[ot] = __builtin_amdgcn_mfma_f32_16x16x32_bf16(af.v, bw[cur][ot].v,
                                                              acc[ot], 0, 0, 0);
        if (s + 2 < 8) {                   // prefetch after consumption
            ax[cur][0] = *(const float4*)(xb + (s + 2) * 32);
            ax[cur][1] = *(const float4*)(xb + (s + 2) * 32 + 4);
#pragma unroll
            for (int ot = 0; ot < 4; ot++)
                bw[cur][ot].q =
                    *(const uint4*)(wb + (size_t)ot * 16 * 512 + (s + 2) * 32);
        }
    }
    // C/D layout: col = ot*16 + m, row(within 16) = quad*4 + r
    if (kz) {
#pragma unroll
        for (int ot = 0; ot < 4; ot++)
#pragma unroll
            for (int r = 0; r < 4; r++)
                red[g][quad * 4 + r][ot * 16 + m] = acc[ot][r];
    }
    __syncthreads();
    if (kz) return;
#pragma unroll
    for (int ot = 0; ot < 4; ot++)
#pragma unroll
        for (int r = 0; r < 4; r++)
            acc[ot][r] += red[g][quad * 4 + r][ot * 16 + m];

    // epilogue: s1/s2 (pre-scaled by log2e) via shuffle reduce
    float a1v[4], a2v[4];
#pragma unroll
    for (int ot = 0; ot < 4; ot++) {
        a1v[ot] = a[ot * 16 + m];
        a2v[ot] = a[64 + ot * 16 + m];
    }
    float s1r[4], s2r[4];
#pragma unroll
    for (int r = 0; r < 4; r++) {
        s1r[r] = 0.f; s2r[r] = 0.f;
#pragma unroll
        for (int ot = 0; ot < 4; ot++) {
            s1r[r] = fmaf(acc[ot][r], a1v[ot], s1r[r]);
            s2r[r] = fmaf(acc[ot][r], a2v[ot], s2r[r]);
        }
    }
#pragma unroll
    for (int d = 1; d < 16; d <<= 1) {
#pragma unroll
        for (int r = 0; r < 4; r++) {
            s1r[r] += __shfl_xor(s1r[r], d);
            s2r[r] += __shfl_xor(s2r[r], d);
        }
    }
    if (m == 0) {
#pragma unroll
        for (int r = 0; r < 4; r++) {
            int rr = rt * 64 + g * 16 + quad * 4 + r;
            s1p[b * 4096 + rr] = s1r[r] * LOG2E;
            s2p[b * 4096 + rr] = s2r[r] * LOG2E;
        }
    }
    // h^T bf16 (round-half-up)
#pragma unroll
    for (int ot = 0; ot < 4; ot++) {
        u32 b0 = __float_as_uint(acc[ot][0]) + 0x8000u;
        u32 b1 = __float_as_uint(acc[ot][1]) + 0x8000u;
        u32 b2 = __float_as_uint(acc[ot][2]) + 0x8000u;
        u32 b3 = __float_as_uint(acc[ot][3]) + 0x8000u;
        uint2 u;
        u.x = (b0 >> 16) | (b1 & 0xffff0000u);
        u.y = (b2 >> 16) | (b3 & 0xffff0000u);
        *(uint2*)(h_t + ((size_t)(b * 64 + ot * 16 + m)) * 4096
                  + rt * 64 + g * 16 + quad * 4) = u;
    }
}

// ---------------------------------------------------------------------------
// Kernel 2: fused masked-softmax-numerator GEMM (r9 WIN structure).
// S=8 (2048 WGs = 8 WG/CU = 32 waves/CU; VGPR 56<=64, LDS 18KBx8=144<=160KB)
// for 2x the latency hiding of r10's S=4 — with part stored as BF16 so the
// HBM traffic stays equal to S=4-fp32 (16 MB).
// ---------------------------------------------------------------------------
template <int NSTEP>
__global__ __launch_bounds__(256, 8) void k2_attn(const u16* __restrict__ h_t,
                                                  const u32* __restrict__ mask_t,
                                                  const float* __restrict__ s1p,
                                                  const float* __restrict__ s2p,
                                                  u16* __restrict__ part,
                                                  float* __restrict__ lp) {
    constexpr int JSEG = NSTEP * 32;
    constexpr int T = NSTEP / 2;           // 64-j tiles
    __shared__ u16 hB[2][64 * 64];         // double buffer, xor-swizzled
    __shared__ float s2l[JSEG];
    const int b = blockIdx.y, seg = blockIdx.z, rb = blockIdx.x;
    const int tid = threadIdx.x, wave = tid >> 6, lane = tid & 63;
    const int m = lane & 15, quad = lane >> 4;
    const int row = rb * 64 + wave * 16 + m;
    const int jstart = seg * JSEG;
    const float t1 = s1p[b * 4096 + row];
    const u16* hsrc = h_t + (size_t)b * 64 * 4096 + jstart;
    const u32* mrow = mask_t + (size_t)(jstart >> 5) * 4096 + row;

    for (int t = tid; t < (JSEG >> 2); t += 256)
        ((float4*)s2l)[t] = ((const float4*)(s2p + b * 4096 + jstart))[t];

    f32x4 acc[4], accd;
#pragma unroll
    for (int ot = 0; ot < 4; ot++) acc[ot] = (f32x4){0.f, 0.f, 0.f, 0.f};
    accd = (f32x4){0.f, 0.f, 0.f, 0.f};

    u32 mw[4];
#pragma unroll
    for (int s = 0; s < 4; s++) mw[s] = mrow[(size_t)s * 4096];
    union { u32 u[4]; short8 v; } ones;
#pragma unroll
    for (int p = 0; p < 4; p++) ones.u[p] = 0x3F803F80u;   // bf16 1.0 pairs

    const int cj = tid & 7;                // 16B chunk column (8 j's)
    const int ow = tid >> 3;               // rows ow, ow+32
    uint4 pf[2];
    pf[0] = *(const uint4*)(hsrc + (size_t)ow * 4096 + (cj << 3));
    pf[1] = *(const uint4*)(hsrc + (size_t)(ow + 32) * 4096 + (cj << 3));
    *(uint4*)(hB[0] + (size_t)ow * 64 + ((cj ^ (ow & 7)) << 3)) = pf[0];
    *(uint4*)(hB[0] + (size_t)(ow + 32) * 64 + ((cj ^ ((ow + 32) & 7)) << 3)) = pf[1];
    __syncthreads();                       // tile 0 + s2l ready

    for (int jt = 0; jt < T; jt++) {
        const int cb = jt & 1;
        if (jt + 1 < T) {                  // global prefetch of next 64-j tile
            pf[0] = *(const uint4*)(hsrc + (size_t)ow * 4096 + (jt + 1) * 64 + (cj << 3));
            pf[1] = *(const uint4*)(hsrc + (size_t)(ow + 32) * 4096 + (jt + 1) * 64 + (cj << 3));
        }
#pragma unroll
        for (int ks = 0; ks < 2; ks++) {
            const int s = jt * 2 + ks;
            // consume BEFORE the distance-4 prefetch overwrites the slot
            const u32 mws = mw[s & 3] >> (quad * 8);
            if (s + 4 < NSTEP) mw[(s + 4) & 3] = mrow[(size_t)(s + 4) * 4096];

            const float4 sa = *(const float4*)&s2l[s * 32 + quad * 8];
            const float4 sb = *(const float4*)&s2l[s * 32 + quad * 8 + 4];
            const float sv[8] = {sa.x, sa.y, sa.z, sa.w, sb.x, sb.y, sb.z, sb.w};
            union { u32 u[4]; short8 v; } af;
#pragma unroll
            for (int p = 0; p < 4; p++) {
                float t0 = t1 + sv[2 * p];
                float u0 = fmaxf(t0, 0.2f * t0);                     // leaky-relu (log2 dom)
                float w0 = __builtin_amdgcn_exp2f(u0);
                u32 m0 = (u32)(((int)(mws << (31 - 2 * p))) >> 31);  // bit -> all-ones/0
                u32 w0u = __float_as_uint(w0) & m0;                  // masked -> +0.0
                float t2 = t1 + sv[2 * p + 1];
                float u2 = fmaxf(t2, 0.2f * t2);
                float w1 = __builtin_amdgcn_exp2f(u2);
                u32 m1 = (u32)(((int)(mws << (30 - 2 * p))) >> 31);
                u32 w1u = __float_as_uint(w1) & m1;
                af.u[p] = __builtin_amdgcn_perm(w1u, w0u, 0x07060302u);  // bf16 truncate
            }
            const int jc = ks * 4 + quad;
#pragma unroll
            for (int ot = 0; ot < 4; ot++) {
                const int o = ot * 16 + m;
                short8 bfv = *(const short8*)(hB[cb] + (size_t)o * 64 + ((jc ^ (o & 7)) << 3));
                acc[ot] = __builtin_amdgcn_mfma_f32_16x16x32_bf16(af.v, bfv, acc[ot], 0, 0, 0);
            }
            accd = __builtin_amdgcn_mfma_f32_16x16x32_bf16(af.v, ones.v, accd, 0, 0, 0);
        }
        if (jt + 1 < T) {                  // stage next tile into the idle buffer
            const int nb = cb ^ 1;
            *(uint4*)(hB[nb] + (size_t)ow * 64 + ((cj ^ (ow & 7)) << 3)) = pf[0];
            *(uint4*)(hB[nb] + (size_t)(ow + 32) * 64 + ((cj ^ ((ow + 32) & 7)) << 3)) = pf[1];
        }
        __syncthreads();
    }
    // C/D layout: col=lane&15, row=quad*4+reg; partials stored bf16 (RNE-ish)
    u16* pb = part + (((size_t)(seg * 4 + b) * 4096) + rb * 64 + wave * 16) * 64;
#pragma unroll
    for (int ot = 0; ot < 4; ot++)
#pragma unroll
        for (int r = 0; r < 4; r++) {
            u32 v = __float_as_uint(acc[ot][r]) + 0x8000u;
            pb[(quad * 4 + r) * 64 + ot * 16 + m] = (u16)(v >> 16);
        }
    if (m == 0) {                          // accd cols all equal; rows quad*4+r
        float* lpb = lp + (size_t)(seg * 4 + b) * 4096 + rb * 64 + wave * 16 + quad * 4;
#pragma unroll
        for (int r = 0; r < 4; r++) lpb[r] = accd[r];
    }
}

// ---------------------------------------------------------------------------
// Kernel 3: combine j-split bf16 partials, normalize, elu.
// ---------------------------------------------------------------------------
template <int S>
__global__ __launch_bounds__(256) void k3_fin(const u16* __restrict__ part,
                                              const float* __restrict__ lp,
                                              float* __restrict__ out) {
    int idx = blockIdx.x * 256 + threadIdx.x;    // 262144 = 4*4096*16
    int o4 = (idx & 15) << 2;
    int bi = idx >> 4;
    uint2 pv[S];
    float lv[S];
#pragma unroll
    for (int s = 0; s < S; s++) {
        pv[s] = *(const uint2*)&part[((size_t)s * 16384 + bi) * 64 + o4];
        lv[s] = lp[(size_t)s * 16384 + bi];
    }
    float p0 = 0.f, p1 = 0.f, p2 = 0.f, p3 = 0.f, l = 0.f;
#pragma unroll
    for (int s = 0; s < S; s++) {
        p0 += __uint_as_float(pv[s].x << 16);
        p1 += __uint_as_float(pv[s].x & 0xffff0000u);
        p2 += __uint_as_float(pv[s].y << 16);
        p3 += __uint_as_float(pv[s].y & 0xffff0000u);
        l += lv[s];
    }
    float rl = 1.f / l;
    p0 *= rl; p1 *= rl; p2 *= rl; p3 *= rl;
    float4 o;
    o.x = p0 > 0.f ? p0 : __builtin_amdgcn_exp2f(p0 * LOG2E) - 1.f;
    o.y = p1 > 0.f ? p1 : __builtin_amdgcn_exp2f(p1 * LOG2E) - 1.f;
    o.z = p2 > 0.f ? p2 : __builtin_amdgcn_exp2f(p2 * LOG2E) - 1.f;
    o.w = p3 > 0.f ? p3 : __builtin_amdgcn_exp2f(p3 * LOG2E) - 1.f;
    *(float4*)&out[(size_t)bi * 64 + o4] = o;
}

// ---------------------------------------------------------------------------
extern "C" void kernel_launch(void* const* d_in, const int* in_sizes, int n_in,
                              void* d_out, int out_size, void* d_ws, size_t ws_size,
                              hipStream_t stream) {
    const float* x  = (const float*)d_in[0];
    const int* adj  = (const int*)d_in[1];
    const float* W  = (const float*)d_in[2];
    const float* a  = (const float*)d_in[3];
    float* out = (float*)d_out;
    char* ws = (char*)d_ws;

    // workspace layout
    u16* h_t   = (u16*)ws;                         // 2 MB
    u32* maskt = (u32*)(ws + (2 << 20));           // 2 MB
    float* s1p = (float*)(ws + (4 << 20));         // 64 KB
    float* s2p = s1p + 16384;                      // 64 KB
    float* lp  = s2p + 16384;                      // S*64 KB (1 float/row)
    size_t base = (4u << 20) + 2 * 65536;
    int S = 8;                                     // k2 j-split: 2048 WGs = 8 WG/CU
    while (S > 1 && base + (size_t)S * (65536 + 2097152) + 65536 > ws_size) S >>= 1;
    u16* part = (u16*)(ws + base + (size_t)S * 65536);        // S*2 MB (bf16)
    u16* wtp = (u16*)(ws + base + (size_t)S * 65536 + (size_t)S * 2097152);  // 64 KB

    prep_kernel<<<2080, 256, 0, stream>>>(adj, maskt, W, wtp);
    k1f<<<dim3(64, 4), 512, 0, stream>>>(x, wtp, a, h_t, s1p, s2p);
    if (S == 8)      k2_attn<16><<<dim3(64, 4, 8), 256, 0, stream>>>(h_t, maskt, s1p, s2p, part, lp);
    else if (S == 4) k2_attn<32><<<dim3(64, 4, 4), 256, 0, stream>>>(h_t, maskt, s1p, s2p, part, lp);
    else if (S == 2) k2_attn<64><<<dim3(64, 4, 2), 256, 0, stream>>>(h_t, maskt, s1p, s2p, part, lp);
    else             k2_attn<128><<<dim3(64, 4, 1), 256, 0, stream>>>(h_t, maskt, s1p, s2p, part, lp);
    if (S == 8)      k3_fin<8><<<1024, 256, 0, stream>>>(part, lp, out);
    else if (S == 4) k3_fin<4><<<1024, 256, 0, stream>>>(part, lp, out);
    else if (S == 2) k3_fin<2><<<1024, 256, 0, stream>>>(part, lp, out);
    else             k3_fin<1><<<1024, 256, 0, stream>>>(part, lp, out);
}